// Round 4
// baseline (50.368 us; speedup 1.0000x reference)
//
#include <hip/hip_runtime.h>
#include <math.h>

// Problem constants (reference: B,D,E,H = 4,128,512,512)
#define BATCH 4
#define DDIM  128
#define EDIM  512
#define HDIM  512

// c = 2*log2(e): P=exp2(c*dec_t), Q=exp2(c*enc_t) so e^{2(dec+enc)} = P*Q
#define TANH_SCALE 2.8853900817779268f

typedef short short8v __attribute__((ext_vector_type(8)));
typedef float f32x4   __attribute__((ext_vector_type(4)));

#define EXP2F(x) __builtin_amdgcn_exp2f(x)
#define RCPF(x)  __builtin_amdgcn_rcpf(x)

// fp32 -> bf16 bits, round-to-nearest-even (inputs are finite/sane)
static __device__ inline unsigned short f2bf(float f) {
    unsigned u = __float_as_uint(f);
    return (unsigned short)((u + 0x7FFFu + ((u >> 16) & 1u)) >> 16);
}

static __device__ inline void gload_lds16(const void* g, void* lds) {
    __builtin_amdgcn_global_load_lds(
        (const __attribute__((address_space(1))) void*)g,
        (__attribute__((address_space(3))) void*)lds, 16, 0, 0);
}

// ---------------------------------------------------------------------------
// One-shot fp32 -> bf16 convert of all four inputs into concatenated ws
// region. Element layout: [xdec (262144) | xenc (1048576) | W1 | W2].
// 896 blocks x 256 threads x 8 elems.
// ---------------------------------------------------------------------------
__global__ __launch_bounds__(256)
void cvt_all(const float* __restrict__ xdec, const float* __restrict__ xenc,
             const float* __restrict__ W1, const float* __restrict__ W2,
             unsigned short* __restrict__ out) {
    const int i8 = (blockIdx.x * 256 + threadIdx.x) * 8;
    const float* src;
    int lo;
    if (i8 < 262144)       { src = xdec; lo = i8; }
    else if (i8 < 1310720) { src = xenc; lo = i8 - 262144; }
    else if (i8 < 1572864) { src = W1;   lo = i8 - 1310720; }
    else                   { src = W2;   lo = i8 - 1572864; }
    float4 f0 = *(const float4*)(src + lo);
    float4 f1 = *(const float4*)(src + lo + 4);
    short8v o;
    o[0] = (short)f2bf(f0.x); o[1] = (short)f2bf(f0.y);
    o[2] = (short)f2bf(f0.z); o[3] = (short)f2bf(f0.w);
    o[4] = (short)f2bf(f1.x); o[5] = (short)f2bf(f1.y);
    o[6] = (short)f2bf(f1.z); o[7] = (short)f2bf(f1.w);
    *(short8v*)(out + i8) = o;
}

// ---------------------------------------------------------------------------
// bf16 MFMA GEMM pair (NT), epilogue exp2(c*acc). 64x128 tile, BK=32,
// 256 threads = 4 waves (2m x 2n), wave tile 32x64 (2x4 frags of 16x16x32).
// Staging via global_load_lds(16B): LDS linear dest, 16B-slot XOR swizzle
// (slot = c16 ^ (row&3)) applied on BOTH the global source address and the
// ds_read side (rule: both-sides-or-neither).
//   blocks 0..31   : P[b,d,h] = exp2(c * sum_k xdec[b,d,k]*W2[h,k])
//   blocks 32..159 : Q[b,h,e] = exp2(c * sum_k W1[h,k]*xenc[b,e,k])
// ---------------------------------------------------------------------------
__global__ __launch_bounds__(256)
void gemm_both(const unsigned short* __restrict__ xdec,
               const unsigned short* __restrict__ xenc,
               const unsigned short* __restrict__ W1,
               const unsigned short* __restrict__ W2,
               float* __restrict__ P, float* __restrict__ Q) {
    __shared__ __align__(16) unsigned short As[64 * 32];    // 4 KB
    __shared__ __align__(16) unsigned short Bs[128 * 32];   // 8 KB

    const int id = blockIdx.x;
    const unsigned short *Ab, *Bb;
    float* Cb;
    int m0, n0;
    if (id < 32) {                 // dec: 4b x 2m x 4n
        int b = id >> 3, r = id & 7;
        m0 = (r >> 2) * 64; n0 = (r & 3) * 128;
        Ab = xdec + b * DDIM * HDIM;
        Bb = W2;
        Cb = P + (long)b * DDIM * HDIM;
    } else {                       // enc: 4b x 8m(h) x 4n(e)
        int t2 = id - 32;
        int b = t2 >> 5, r = t2 & 31;
        m0 = (r >> 2) * 64; n0 = (r & 3) * 128;
        Ab = W1;
        Bb = xenc + b * EDIM * HDIM;
        Cb = Q + (long)b * HDIM * EDIM;
    }

    const int t   = threadIdx.x;
    const int wid = t >> 6;             // 0..3
    const int wm  = wid >> 1, wn = wid & 1;
    const int l   = t & 63;
    const int lr  = l & 15;             // fragment row within 16
    const int c16 = l >> 4;             // fragment 16B k-column (0..3)

    // staging: within a 16-row chunk, lane l -> row l>>2, slot l&3;
    // source column-group pre-swizzled so linear LDS ends up swizzled
    const int srow = l >> 2;
    const int scg  = (l & 3) ^ (srow & 3);

    f32x4 acc[2][4] = {};

    for (int k0 = 0; k0 < HDIM; k0 += 32) {
        // wave w stages A-chunk w and B-chunks w, w+4 (chunk = 16 rows = 1KB)
        {
            const unsigned short* g =
                Ab + (long)(m0 + wid * 16 + srow) * HDIM + k0 + scg * 8;
            gload_lds16(g, As + wid * 512);
        }
        {
            const unsigned short* g =
                Bb + (long)(n0 + wid * 16 + srow) * HDIM + k0 + scg * 8;
            gload_lds16(g, Bs + wid * 512);
        }
        {
            const unsigned short* g =
                Bb + (long)(n0 + (wid + 4) * 16 + srow) * HDIM + k0 + scg * 8;
            gload_lds16(g, Bs + (wid + 4) * 512);
        }
        __syncthreads();   // drains vmcnt+lgkmcnt

        short8v af[2], bf[4];
        #pragma unroll
        for (int fm = 0; fm < 2; ++fm) {
            int row = wm * 32 + fm * 16 + lr;
            af[fm] = *(const short8v*)(As + row * 32 + ((c16 ^ (row & 3)) * 8));
        }
        #pragma unroll
        for (int fn = 0; fn < 4; ++fn) {
            int row = wn * 64 + fn * 16 + lr;
            bf[fn] = *(const short8v*)(Bs + row * 32 + ((c16 ^ (row & 3)) * 8));
        }
        #pragma unroll
        for (int fm = 0; fm < 2; ++fm)
            #pragma unroll
            for (int fn = 0; fn < 4; ++fn)
                acc[fm][fn] = __builtin_amdgcn_mfma_f32_16x16x32_bf16(
                    af[fm], bf[fn], acc[fm][fn], 0, 0, 0);
        __syncthreads();
    }

    // epilogue: D[row=(l>>4)*4+r][col=l&15] -> exp2(c * acc)
    const int crow = c16 * 4;
    #pragma unroll
    for (int fm = 0; fm < 2; ++fm)
        #pragma unroll
        for (int fn = 0; fn < 4; ++fn)
            #pragma unroll
            for (int r = 0; r < 4; ++r) {
                int rr = m0 + wm * 32 + fm * 16 + crow + r;
                int cc = n0 + wn * 64 + fn * 16 + lr;
                Cb[(long)rr * 512 + cc] = EXP2F(TANH_SCALE * acc[fm][fn][r]);
            }
}

// ---------------------------------------------------------------------------
// Fused tanh-dot + masked log_softmax, 2 decoder rows per block (UNCHANGED
// from round 3 for clean A/B on the GEMM restructure).
//   val_e = sum_h (-2 v[h]) * rcp(1 + P[d,h]*Q[h,e])
// ---------------------------------------------------------------------------
__global__ __launch_bounds__(512)
void attn_lsm(const float* __restrict__ P,             // (B,D,H) exp2-form
              const float* __restrict__ Q,             // (B,H,E) exp2-form
              const unsigned char* __restrict__ mask,  // (B,E)
              const float* __restrict__ vw,            // (H)
              float* __restrict__ out) {               // (B,D,E)
    const int p   = blockIdx.x;       // 0..255: (b, d-pair)
    const int bd0 = p * 2;
    const int b   = bd0 / DDIM;
    const int e   = threadIdx.x;      // 0..511

    __shared__ float2 dec_s[HDIM];    // {P[d0][h], P[d0+1][h]}
    __shared__ float  v2_s[HDIM];     // -2*v[h]
    __shared__ float  red0[8], red1[8];

    dec_s[e] = make_float2(P[(long)bd0 * HDIM + e],
                           P[(long)(bd0 + 1) * HDIM + e]);
    v2_s[e]  = -2.0f * vw[e];
    __syncthreads();

    const float* qp = Q + (long)b * HDIM * EDIM + e;
    float acc0 = 0.f, acc1 = 0.f;
    #pragma unroll 8
    for (int h = 0; h < HDIM; ++h, qp += EDIM) {
        float  q = *qp;
        float2 d = dec_s[h];
        float v2 = v2_s[h];
        acc0 = fmaf(v2, RCPF(fmaf(d.x, q, 1.0f)), acc0);
        acc1 = fmaf(v2, RCPF(fmaf(d.y, q, 1.0f)), acc1);
    }

    const bool mk = mask[b * EDIM + e];
    float val0 = mk ? -INFINITY : acc0;
    float val1 = mk ? -INFINITY : acc1;

    const int wid = e >> 6, lid = e & 63;

    float m0 = val0, m1 = val1;
    #pragma unroll
    for (int o = 32; o >= 1; o >>= 1) {
        m0 = fmaxf(m0, __shfl_xor(m0, o));
        m1 = fmaxf(m1, __shfl_xor(m1, o));
    }
    if (lid == 0) { red0[wid] = m0; red1[wid] = m1; }
    __syncthreads();
    m0 = red0[0]; m1 = red1[0];
    #pragma unroll
    for (int i = 1; i < 8; ++i) { m0 = fmaxf(m0, red0[i]); m1 = fmaxf(m1, red1[i]); }
    __syncthreads();

    float s0 = __expf(val0 - m0), s1 = __expf(val1 - m1);
    #pragma unroll
    for (int o = 32; o >= 1; o >>= 1) {
        s0 += __shfl_xor(s0, o);
        s1 += __shfl_xor(s1, o);
    }
    if (lid == 0) { red0[wid] = s0; red1[wid] = s1; }
    __syncthreads();
    float tot0 = 0.f, tot1 = 0.f;
    #pragma unroll
    for (int i = 0; i < 8; ++i) { tot0 += red0[i]; tot1 += red1[i]; }

    out[(long)bd0 * EDIM + e]       = val0 - m0 - __logf(tot0);
    out[(long)(bd0 + 1) * EDIM + e] = val1 - m1 - __logf(tot1);
}

// ---------------------------------------------------------------------------
extern "C" void kernel_launch(void* const* d_in, const int* in_sizes, int n_in,
                              void* d_out, int out_size, void* d_ws, size_t ws_size,
                              hipStream_t stream) {
    const float*         xdec = (const float*)d_in[0];         // (B,D,H)
    const float*         xenc = (const float*)d_in[1];         // (B,E,H)
    const unsigned char* mask = (const unsigned char*)d_in[2]; // (B,E)
    const float*         W1   = (const float*)d_in[3];         // (H,H)
    const float*         W2   = (const float*)d_in[4];         // (H,H)
    const float*         vw   = (const float*)d_in[5];         // (H)
    float*               out  = (float*)d_out;                 // (B,D,E)

    float* P = (float*)d_ws;                                   // 262144 f
    float* Q = P + 262144;                                     // 1048576 f
    unsigned short* bf = (unsigned short*)(Q + 1048576);       // 1835008 h
    unsigned short* xdec_bf = bf;                              // 262144
    unsigned short* xenc_bf = bf + 262144;                     // 1048576
    unsigned short* W1_bf   = bf + 1310720;                    // 262144
    unsigned short* W2_bf   = bf + 1572864;                    // 262144

    cvt_all<<<896, 256, 0, stream>>>(xdec, xenc, W1, W2, bf);
    gemm_both<<<160, 256, 0, stream>>>(xdec_bf, xenc_bf, W1_bf, W2_bf, P, Q);
    attn_lsm<<<BATCH * DDIM / 2, 512, 0, stream>>>(P, Q, mask, vw, out);
}

// Round 5
// 47.493 us; speedup vs baseline: 1.0605x; 1.0605x over previous
//
#include <hip/hip_runtime.h>
#include <math.h>

// Problem constants (reference: B,D,E,H = 4,128,512,512)
#define BATCH 4
#define DDIM  128
#define EDIM  512
#define HDIM  512

// c = 2*log2(e): P=exp2(c*dec_t), Q=exp2(c*enc_t) so e^{2(dec+enc)} = P*Q
#define TANH_SCALE 2.8853900817779268f

typedef short short8v __attribute__((ext_vector_type(8)));
typedef float f32x4   __attribute__((ext_vector_type(4)));

#define EXP2F(x) __builtin_amdgcn_exp2f(x)
#define RCPF(x)  __builtin_amdgcn_rcpf(x)

// fp32 -> bf16 bits, round-to-nearest-even (inputs are finite/sane)
static __device__ inline unsigned short f2bf(float f) {
    unsigned u = __float_as_uint(f);
    return (unsigned short)((u + 0x7FFFu + ((u >> 16) & 1u)) >> 16);
}

// ---------------------------------------------------------------------------
// Fused bf16-MFMA GEMM pair (NT), epilogue = exp2(c * acc)  [round-3 version]
//   blocks 0..63   : P[b,d,h] = exp2(c * sum_k xdec[b,d,k] * W2[h,k])
//   blocks 64..319 : Q[b,h,e] = exp2(c * sum_k W1[h,k]   * xenc[b,e,k])
// 64x64 tile, BK=32, 256 threads = 4 waves (2x2), wave = 2x2 frags of
// 16x16x32.
// ---------------------------------------------------------------------------
__global__ __launch_bounds__(256)
void gemm_both(const float* __restrict__ xdec, const float* __restrict__ W2,
               const float* __restrict__ xenc, const float* __restrict__ W1,
               float* __restrict__ P, float* __restrict__ Q) {
    __shared__ unsigned short As[64][40];  // 80B rows: 16B-aligned, bank-spread
    __shared__ unsigned short Bs[64][40];

    const int id = blockIdx.x;
    const float *Ab, *Bb;
    float* Cb;
    int m0, n0;
    if (id < 64) {                    // dec task: 4b x 2mb x 8nb
        int b = id >> 4, r = id & 15;
        m0 = (r >> 3) * 64; n0 = (r & 7) * 64;
        Ab = xdec + (long)b * DDIM * HDIM;
        Bb = W2;
        Cb = P + (long)b * DDIM * HDIM;
    } else {                          // enc task: 4b x 8mb(h) x 8nb(e)
        int t2 = id - 64;
        int b = t2 >> 6, r = t2 & 63;
        m0 = (r >> 3) * 64; n0 = (r & 7) * 64;
        Ab = W1;
        Bb = xenc + (long)b * EDIM * HDIM;
        Cb = Q + (long)b * HDIM * EDIM;
    }

    const int t    = threadIdx.x;
    const int srow = t >> 2;          // 0..63 staging row
    const int skq  = (t & 3) << 3;    // 0,8,16,24 staging k-offset

    const int wid = t >> 6;
    const int wm  = wid >> 1, wn = wid & 1;
    const int l   = t & 63;
    const int lr  = l & 15;           // fragment row within 16
    const int lk  = (l >> 4) << 3;    // fragment k-offset

    f32x4 acc[2][2] = {};

    const float* ap = Ab + (long)(m0 + srow) * HDIM + skq;
    const float* bp = Bb + (long)(n0 + srow) * HDIM + skq;

    for (int k0 = 0; k0 < HDIM; k0 += 32, ap += 32, bp += 32) {
        float4 a0 = *(const float4*)ap, a1 = *(const float4*)(ap + 4);
        float4 b0 = *(const float4*)bp, b1 = *(const float4*)(bp + 4);
        unsigned short* aw = &As[srow][skq];
        unsigned short* bw = &Bs[srow][skq];
        aw[0] = f2bf(a0.x); aw[1] = f2bf(a0.y); aw[2] = f2bf(a0.z); aw[3] = f2bf(a0.w);
        aw[4] = f2bf(a1.x); aw[5] = f2bf(a1.y); aw[6] = f2bf(a1.z); aw[7] = f2bf(a1.w);
        bw[0] = f2bf(b0.x); bw[1] = f2bf(b0.y); bw[2] = f2bf(b0.z); bw[3] = f2bf(b0.w);
        bw[4] = f2bf(b1.x); bw[5] = f2bf(b1.y); bw[6] = f2bf(b1.z); bw[7] = f2bf(b1.w);
        __syncthreads();

        short8v af[2], bf[2];
        #pragma unroll
        for (int fm = 0; fm < 2; ++fm)
            af[fm] = *(const short8v*)&As[wm * 32 + fm * 16 + lr][lk];
        #pragma unroll
        for (int fn = 0; fn < 2; ++fn)
            bf[fn] = *(const short8v*)&Bs[wn * 32 + fn * 16 + lr][lk];
        #pragma unroll
        for (int fm = 0; fm < 2; ++fm)
            #pragma unroll
            for (int fn = 0; fn < 2; ++fn)
                acc[fm][fn] = __builtin_amdgcn_mfma_f32_16x16x32_bf16(
                    af[fm], bf[fn], acc[fm][fn], 0, 0, 0);
        __syncthreads();
    }

    // epilogue: C[row=(l>>4)*4+r][col=l&15] = exp2(c * acc)
    const int crow = (l >> 4) << 2;
    #pragma unroll
    for (int fm = 0; fm < 2; ++fm)
        #pragma unroll
        for (int fn = 0; fn < 2; ++fn)
            #pragma unroll
            for (int r = 0; r < 4; ++r) {
                int rr = m0 + wm * 32 + fm * 16 + crow + r;
                int cc = n0 + wn * 32 + fn * 16 + lr;
                Cb[(long)rr * 512 + cc] = EXP2F(TANH_SCALE * acc[fm][fn][r]);
            }
}

// ---------------------------------------------------------------------------
// Fused tanh-dot + masked log_softmax, 2 decoder rows per block.
//   val_e = sum_h (-2 v[h]) * rcp(1 + P[d,h]*Q[h,e])
// XCD-affinity mapping: xcd = blockIdx&7 (HW round-robin), batch = xcd&3,
// so all 32 blocks on an XCD read the SAME 1MB Q panel -> it stays resident
// in that XCD's 4MB L2 (instead of 256MB of LLC traffic with random
// placement). d-pair = (blockIdx>>3) + 32*(xcd>>2) keeps the map bijective.
// ---------------------------------------------------------------------------
__global__ __launch_bounds__(512)
void attn_lsm(const float* __restrict__ P,             // (B,D,H) exp2-form
              const float* __restrict__ Q,             // (B,H,E) exp2-form
              const unsigned char* __restrict__ mask,  // (B,E)
              const float* __restrict__ vw,            // (H)
              float* __restrict__ out) {               // (B,D,E)
    const int pb   = blockIdx.x;      // 0..255
    const int xcd  = pb & 7;
    const int b    = xcd & 3;
    const int dp   = (pb >> 3) + ((xcd >> 2) << 5);   // 0..63
    const int bd0  = b * DDIM + dp * 2;
    const int e    = threadIdx.x;     // 0..511

    __shared__ float4 combo[HDIM];    // {P[d0][h], P[d0+1][h], -2v[h], pad}
    __shared__ float  red0[8], red1[8];

    combo[e] = make_float4(P[(long)bd0 * HDIM + e],
                           P[(long)(bd0 + 1) * HDIM + e],
                           -2.0f * vw[e], 0.0f);
    __syncthreads();

    const float* qp = Q + (long)b * HDIM * EDIM + e;
    float acc0 = 0.f, acc1 = 0.f;
    #pragma unroll 8
    for (int h = 0; h < HDIM; ++h, qp += EDIM) {
        float  q = *qp;
        float4 c = combo[h];
        acc0 = fmaf(c.z, RCPF(fmaf(c.x, q, 1.0f)), acc0);
        acc1 = fmaf(c.z, RCPF(fmaf(c.y, q, 1.0f)), acc1);
    }

    const bool mk = mask[b * EDIM + e];
    float val0 = mk ? -INFINITY : acc0;
    float val1 = mk ? -INFINITY : acc1;

    const int wid = e >> 6, lid = e & 63;

    // --- block max (both channels) ---
    float m0 = val0, m1 = val1;
    #pragma unroll
    for (int o = 32; o >= 1; o >>= 1) {
        m0 = fmaxf(m0, __shfl_xor(m0, o));
        m1 = fmaxf(m1, __shfl_xor(m1, o));
    }
    if (lid == 0) { red0[wid] = m0; red1[wid] = m1; }
    __syncthreads();
    m0 = red0[0]; m1 = red1[0];
    #pragma unroll
    for (int i = 1; i < 8; ++i) { m0 = fmaxf(m0, red0[i]); m1 = fmaxf(m1, red1[i]); }
    __syncthreads();  // reuse red[]

    // --- block sum of exp(val - m) ---
    float s0 = __expf(val0 - m0), s1 = __expf(val1 - m1);
    #pragma unroll
    for (int o = 32; o >= 1; o >>= 1) {
        s0 += __shfl_xor(s0, o);
        s1 += __shfl_xor(s1, o);
    }
    if (lid == 0) { red0[wid] = s0; red1[wid] = s1; }
    __syncthreads();
    float tot0 = 0.f, tot1 = 0.f;
    #pragma unroll
    for (int i = 0; i < 8; ++i) { tot0 += red0[i]; tot1 += red1[i]; }

    out[(long)bd0 * EDIM + e]       = val0 - m0 - __logf(tot0);
    out[(long)(bd0 + 1) * EDIM + e] = val1 - m1 - __logf(tot1);
}

// ---------------------------------------------------------------------------
extern "C" void kernel_launch(void* const* d_in, const int* in_sizes, int n_in,
                              void* d_out, int out_size, void* d_ws, size_t ws_size,
                              hipStream_t stream) {
    const float*         xdec = (const float*)d_in[0];         // (B,D,H)
    const float*         xenc = (const float*)d_in[1];         // (B,E,H)
    const unsigned char* mask = (const unsigned char*)d_in[2]; // (B,E)
    const float*         W1   = (const float*)d_in[3];         // (H,H)
    const float*         W2   = (const float*)d_in[4];         // (H,H)
    const float*         vw   = (const float*)d_in[5];         // (H)
    float*               out  = (float*)d_out;                 // (B,D,E)

    float* P = (float*)d_ws;                                   // B*D*H
    float* Q = P + (size_t)BATCH * DDIM * HDIM;                // B*H*E

    gemm_both<<<64 + 256, 256, 0, stream>>>(xdec, W2, xenc, W1, P, Q);
    attn_lsm<<<BATCH * DDIM / 2, 512, 0, stream>>>(P, Q, mask, vw, out);
}

// Round 6
// 46.930 us; speedup vs baseline: 1.0733x; 1.0120x over previous
//
#include <hip/hip_runtime.h>
#include <math.h>

// Problem constants (reference: B,D,E,H = 4,128,512,512)
#define BATCH 4
#define DDIM  128
#define EDIM  512
#define HDIM  512

// c = 2*log2(e): P=exp2(c*dec_t), Q=exp2(c*enc_t) so e^{2(dec+enc)} = P*Q
#define TANH_SCALE 2.8853900817779268f

typedef short short8v __attribute__((ext_vector_type(8)));
typedef float f32x4   __attribute__((ext_vector_type(4)));

#define EXP2F(x) __builtin_amdgcn_exp2f(x)
#define RCPF(x)  __builtin_amdgcn_rcpf(x)

// fp32 -> bf16 bits, round-to-nearest-even
static __device__ inline unsigned short f2bf(float f) {
    unsigned u = __float_as_uint(f);
    return (unsigned short)((u + 0x7FFFu + ((u >> 16) & 1u)) >> 16);
}
// pack two fp32 -> one u32 holding {bf16(f1) : bf16(f0)} (f0 in low half)
static __device__ inline unsigned pack_bf2(float f0, float f1) {
    unsigned u0 = __float_as_uint(f0), u1 = __float_as_uint(f1);
    u0 += 0x7FFFu + ((u0 >> 16) & 1u);
    u1 += 0x7FFFu + ((u1 >> 16) & 1u);
    // bytes [3:2]<-u1 hi16, [1:0]<-u0 hi16
    return __builtin_amdgcn_perm(u1, u0, 0x07060302u);
}
// bf16 bits -> fp32
static __device__ inline float bf2f(unsigned short h) {
    return __uint_as_float(((unsigned)h) << 16);
}

// ---------------------------------------------------------------------------
// bf16 MFMA GEMM pair (NT), epilogue bf16(exp2(c*acc)). 64x128 tile, BK=32,
// 256 threads = 4 waves (2m x 2n), wave tile 32x64 = 2x4 frags of 16x16x32.
// Staging: fp32 global reads, v_perm-packed bf16 pairs, ds_write_b128
// (1 write per 8 elems instead of 8 scalar b16 writes). 80B LDS rows keep
// 16B alignment and spread fragment-read banks (2-way, free).
//   blocks 0..31   : P[b,d,h] = exp2(c * sum_k xdec[b,d,k]*W2[h,k])
//   blocks 32..159 : Q[b,h,e] = exp2(c * sum_k W1[h,k]*xenc[b,e,k])
// ---------------------------------------------------------------------------
__global__ __launch_bounds__(256)
void gemm_both(const float* __restrict__ xdec, const float* __restrict__ W2,
               const float* __restrict__ xenc, const float* __restrict__ W1,
               unsigned short* __restrict__ P, unsigned short* __restrict__ Q) {
    __shared__ unsigned short As[64][40];    // 5 KB
    __shared__ unsigned short Bs[128][40];   // 10 KB

    const int id = blockIdx.x;
    const float *Ab, *Bb;
    unsigned short* Cb;
    int m0, n0;
    if (id < 32) {                 // dec: 4b x 2m(d) x 4n(h)
        int b = id >> 3, r = id & 7;
        m0 = (r >> 2) * 64; n0 = (r & 3) * 128;
        Ab = xdec + (long)b * DDIM * HDIM;
        Bb = W2;
        Cb = P + (long)b * DDIM * HDIM;
    } else {                       // enc: 4b x 8m(h) x 4n(e)
        int t2 = id - 32;
        int b = t2 >> 5, r = t2 & 31;
        m0 = (r >> 2) * 64; n0 = (r & 3) * 128;
        Ab = W1;
        Bb = xenc + (long)b * EDIM * HDIM;
        Cb = Q + (long)b * HDIM * EDIM;
    }

    const int t    = threadIdx.x;
    const int arow = t >> 2, ak = (t & 3) << 3;   // A: 8 elems of one row
    const int brow = t >> 1, bk = (t & 1) << 4;   // B: 16 elems of one row

    const int wid = t >> 6, wm = wid >> 1, wn = wid & 1;
    const int l   = t & 63, lr = l & 15, c16 = l >> 4;

    f32x4 acc[2][4] = {};

    const float* ap = Ab + (long)(m0 + arow) * HDIM + ak;
    const float* bp = Bb + (long)(n0 + brow) * HDIM + bk;

    for (int k0 = 0; k0 < HDIM; k0 += 32, ap += 32, bp += 32) {
        float4 a0 = *(const float4*)ap, a1 = *(const float4*)(ap + 4);
        float4 b0 = *(const float4*)bp, b1 = *(const float4*)(bp + 4);
        float4 b2 = *(const float4*)(bp + 8), b3 = *(const float4*)(bp + 12);
        uint4 apk, bpk0, bpk1;
        apk.x  = pack_bf2(a0.x, a0.y); apk.y  = pack_bf2(a0.z, a0.w);
        apk.z  = pack_bf2(a1.x, a1.y); apk.w  = pack_bf2(a1.z, a1.w);
        bpk0.x = pack_bf2(b0.x, b0.y); bpk0.y = pack_bf2(b0.z, b0.w);
        bpk0.z = pack_bf2(b1.x, b1.y); bpk0.w = pack_bf2(b1.z, b1.w);
        bpk1.x = pack_bf2(b2.x, b2.y); bpk1.y = pack_bf2(b2.z, b2.w);
        bpk1.z = pack_bf2(b3.x, b3.y); bpk1.w = pack_bf2(b3.z, b3.w);
        *(uint4*)&As[arow][ak]     = apk;
        *(uint4*)&Bs[brow][bk]     = bpk0;
        *(uint4*)&Bs[brow][bk + 8] = bpk1;
        __syncthreads();

        short8v af[2], bf[4];
        #pragma unroll
        for (int fm = 0; fm < 2; ++fm)
            af[fm] = *(const short8v*)&As[wm * 32 + fm * 16 + lr][c16 * 8];
        #pragma unroll
        for (int fn = 0; fn < 4; ++fn)
            bf[fn] = *(const short8v*)&Bs[wn * 64 + fn * 16 + lr][c16 * 8];
        #pragma unroll
        for (int fm = 0; fm < 2; ++fm)
            #pragma unroll
            for (int fn = 0; fn < 4; ++fn)
                acc[fm][fn] = __builtin_amdgcn_mfma_f32_16x16x32_bf16(
                    af[fm], bf[fn], acc[fm][fn], 0, 0, 0);
        __syncthreads();
    }

    // epilogue: D[row=c16*4+r][col=lr] -> bf16(exp2(c * acc))
    const int crow = c16 << 2;
    #pragma unroll
    for (int fm = 0; fm < 2; ++fm)
        #pragma unroll
        for (int fn = 0; fn < 4; ++fn)
            #pragma unroll
            for (int r = 0; r < 4; ++r) {
                int rr = m0 + wm * 32 + fm * 16 + crow + r;
                int cc = n0 + wn * 64 + fn * 16 + lr;
                Cb[(long)rr * 512 + cc] = f2bf(EXP2F(TANH_SCALE * acc[fm][fn][r]));
            }
}

// ---------------------------------------------------------------------------
// Fused tanh-dot + masked log_softmax, 2 decoder rows per block, bf16 P/Q.
//   val_e = sum_h (-2 v[h]) * rcp(1 + P[d,h]*Q[h,e])
// XCD-affinity: xcd=blockIdx&7, batch=xcd&3 -> 32 blocks/XCD share one
// 1MB(->0.5MB bf16) Q panel. 32-bit voffset walk for the Q column.
// ---------------------------------------------------------------------------
__global__ __launch_bounds__(512)
void attn_lsm(const unsigned short* __restrict__ P,    // (B,D,H) bf16 exp2-form
              const unsigned short* __restrict__ Q,    // (B,H,E) bf16 exp2-form
              const unsigned char* __restrict__ mask,  // (B,E)
              const float* __restrict__ vw,            // (H)
              float* __restrict__ out) {               // (B,D,E)
    const int pb   = blockIdx.x;      // 0..255
    const int xcd  = pb & 7;
    const int b    = xcd & 3;
    const int dp   = (pb >> 3) + ((xcd >> 2) << 5);   // 0..63
    const int bd0  = b * DDIM + dp * 2;
    const int e    = threadIdx.x;     // 0..511

    __shared__ float4 combo[HDIM];    // {P[d0][h], P[d0+1][h], -2v[h], pad}
    __shared__ float  red0[8], red1[8];

    combo[e] = make_float4(bf2f(P[(long)bd0 * HDIM + e]),
                           bf2f(P[(long)(bd0 + 1) * HDIM + e]),
                           -2.0f * vw[e], 0.0f);
    __syncthreads();

    const unsigned short* qb = Q + (long)b * HDIM * EDIM;
    int off = e;
    float acc0 = 0.f, acc1 = 0.f;
    #pragma unroll 8
    for (int h = 0; h < HDIM; ++h, off += EDIM) {
        float  q = bf2f(qb[off]);
        float4 c = combo[h];
        acc0 = fmaf(c.z, RCPF(fmaf(c.x, q, 1.0f)), acc0);
        acc1 = fmaf(c.z, RCPF(fmaf(c.y, q, 1.0f)), acc1);
    }

    const bool mk = mask[b * EDIM + e];
    float val0 = mk ? -INFINITY : acc0;
    float val1 = mk ? -INFINITY : acc1;

    const int wid = e >> 6, lid = e & 63;

    // --- block max (both channels) ---
    float m0 = val0, m1 = val1;
    #pragma unroll
    for (int o = 32; o >= 1; o >>= 1) {
        m0 = fmaxf(m0, __shfl_xor(m0, o));
        m1 = fmaxf(m1, __shfl_xor(m1, o));
    }
    if (lid == 0) { red0[wid] = m0; red1[wid] = m1; }
    __syncthreads();
    m0 = red0[0]; m1 = red1[0];
    #pragma unroll
    for (int i = 1; i < 8; ++i) { m0 = fmaxf(m0, red0[i]); m1 = fmaxf(m1, red1[i]); }
    __syncthreads();  // reuse red[]

    // --- block sum of exp(val - m) ---
    float s0 = __expf(val0 - m0), s1 = __expf(val1 - m1);
    #pragma unroll
    for (int o = 32; o >= 1; o >>= 1) {
        s0 += __shfl_xor(s0, o);
        s1 += __shfl_xor(s1, o);
    }
    if (lid == 0) { red0[wid] = s0; red1[wid] = s1; }
    __syncthreads();
    float tot0 = 0.f, tot1 = 0.f;
    #pragma unroll
    for (int i = 0; i < 8; ++i) { tot0 += red0[i]; tot1 += red1[i]; }

    out[(long)bd0 * EDIM + e]       = val0 - m0 - __logf(tot0);
    out[(long)(bd0 + 1) * EDIM + e] = val1 - m1 - __logf(tot1);
}

// ---------------------------------------------------------------------------
extern "C" void kernel_launch(void* const* d_in, const int* in_sizes, int n_in,
                              void* d_out, int out_size, void* d_ws, size_t ws_size,
                              hipStream_t stream) {
    const float*         xdec = (const float*)d_in[0];         // (B,D,H)
    const float*         xenc = (const float*)d_in[1];         // (B,E,H)
    const unsigned char* mask = (const unsigned char*)d_in[2]; // (B,E)
    const float*         W1   = (const float*)d_in[3];         // (H,H)
    const float*         W2   = (const float*)d_in[4];         // (H,H)
    const float*         vw   = (const float*)d_in[5];         // (H)
    float*               out  = (float*)d_out;                 // (B,D,E)

    unsigned short* P = (unsigned short*)d_ws;                 // B*D*H bf16
    unsigned short* Q = P + (size_t)BATCH * DDIM * HDIM;       // B*H*E bf16

    gemm_both<<<160, 256, 0, stream>>>(xdec, W2, xenc, W1, P, Q);
    attn_lsm<<<BATCH * DDIM / 2, 512, 0, stream>>>(P, Q, mask, vw, out);
}

// Round 7
// 42.743 us; speedup vs baseline: 1.1784x; 1.0980x over previous
//
#include <hip/hip_runtime.h>
#include <math.h>

// Problem constants (reference: B,D,E,H = 4,128,512,512)
#define BATCH 4
#define DDIM  128
#define EDIM  512
#define HDIM  512

// c = 2*log2(e): P=exp2(c*dec_t), Q=exp2(c*enc_t) so e^{2(dec+enc)} = P*Q
#define TANH_SCALE 2.8853900817779268f

typedef short short8v __attribute__((ext_vector_type(8)));
typedef float f32x4   __attribute__((ext_vector_type(4)));

#define EXP2F(x) __builtin_amdgcn_exp2f(x)
#define RCPF(x)  __builtin_amdgcn_rcpf(x)

// fp32 -> bf16 bits, round-to-nearest-even
static __device__ inline unsigned short f2bf(float f) {
    unsigned u = __float_as_uint(f);
    return (unsigned short)((u + 0x7FFFu + ((u >> 16) & 1u)) >> 16);
}
// pack two fp32 -> one u32 holding {bf16(f1) : bf16(f0)} (f0 in low half)
static __device__ inline unsigned pack_bf2(float f0, float f1) {
    unsigned u0 = __float_as_uint(f0), u1 = __float_as_uint(f1);
    u0 += 0x7FFFu + ((u0 >> 16) & 1u);
    u1 += 0x7FFFu + ((u1 >> 16) & 1u);
    return __builtin_amdgcn_perm(u1, u0, 0x07060302u);
}
// bf16 bits -> fp32
static __device__ inline float bf2f(unsigned short h) {
    return __uint_as_float(((unsigned)h) << 16);
}

// ---------------------------------------------------------------------------
// bf16 MFMA GEMM pair (NT), epilogue bf16(exp2(c*acc)). UNCHANGED from R6
// for a clean A/B on the attention restructure.
//   blocks 0..31   : P[b,d,h] = exp2(c * sum_k xdec[b,d,k]*W2[h,k])
//   blocks 32..159 : Q[b,h,e] = exp2(c * sum_k W1[h,k]*xenc[b,e,k])
// ---------------------------------------------------------------------------
__global__ __launch_bounds__(256)
void gemm_both(const float* __restrict__ xdec, const float* __restrict__ W2,
               const float* __restrict__ xenc, const float* __restrict__ W1,
               unsigned short* __restrict__ P, unsigned short* __restrict__ Q) {
    __shared__ unsigned short As[64][40];    // 5 KB
    __shared__ unsigned short Bs[128][40];   // 10 KB

    const int id = blockIdx.x;
    const float *Ab, *Bb;
    unsigned short* Cb;
    int m0, n0;
    if (id < 32) {                 // dec: 4b x 2m(d) x 4n(h)
        int b = id >> 3, r = id & 7;
        m0 = (r >> 2) * 64; n0 = (r & 3) * 128;
        Ab = xdec + (long)b * DDIM * HDIM;
        Bb = W2;
        Cb = P + (long)b * DDIM * HDIM;
    } else {                       // enc: 4b x 8m(h) x 4n(e)
        int t2 = id - 32;
        int b = t2 >> 5, r = t2 & 31;
        m0 = (r >> 2) * 64; n0 = (r & 3) * 128;
        Ab = W1;
        Bb = xenc + (long)b * EDIM * HDIM;
        Cb = Q + (long)b * HDIM * EDIM;
    }

    const int t    = threadIdx.x;
    const int arow = t >> 2, ak = (t & 3) << 3;   // A: 8 elems of one row
    const int brow = t >> 1, bk = (t & 1) << 4;   // B: 16 elems of one row

    const int wid = t >> 6, wm = wid >> 1, wn = wid & 1;
    const int l   = t & 63, lr = l & 15, c16 = l >> 4;

    f32x4 acc[2][4] = {};

    const float* ap = Ab + (long)(m0 + arow) * HDIM + ak;
    const float* bp = Bb + (long)(n0 + brow) * HDIM + bk;

    for (int k0 = 0; k0 < HDIM; k0 += 32, ap += 32, bp += 32) {
        float4 a0 = *(const float4*)ap, a1 = *(const float4*)(ap + 4);
        float4 b0 = *(const float4*)bp, b1 = *(const float4*)(bp + 4);
        float4 b2 = *(const float4*)(bp + 8), b3 = *(const float4*)(bp + 12);
        uint4 apk, bpk0, bpk1;
        apk.x  = pack_bf2(a0.x, a0.y); apk.y  = pack_bf2(a0.z, a0.w);
        apk.z  = pack_bf2(a1.x, a1.y); apk.w  = pack_bf2(a1.z, a1.w);
        bpk0.x = pack_bf2(b0.x, b0.y); bpk0.y = pack_bf2(b0.z, b0.w);
        bpk0.z = pack_bf2(b1.x, b1.y); bpk0.w = pack_bf2(b1.z, b1.w);
        bpk1.x = pack_bf2(b2.x, b2.y); bpk1.y = pack_bf2(b2.z, b2.w);
        bpk1.z = pack_bf2(b3.x, b3.y); bpk1.w = pack_bf2(b3.z, b3.w);
        *(uint4*)&As[arow][ak]     = apk;
        *(uint4*)&Bs[brow][bk]     = bpk0;
        *(uint4*)&Bs[brow][bk + 8] = bpk1;
        __syncthreads();

        short8v af[2], bf[4];
        #pragma unroll
        for (int fm = 0; fm < 2; ++fm)
            af[fm] = *(const short8v*)&As[wm * 32 + fm * 16 + lr][c16 * 8];
        #pragma unroll
        for (int fn = 0; fn < 4; ++fn)
            bf[fn] = *(const short8v*)&Bs[wn * 64 + fn * 16 + lr][c16 * 8];
        #pragma unroll
        for (int fm = 0; fm < 2; ++fm)
            #pragma unroll
            for (int fn = 0; fn < 4; ++fn)
                acc[fm][fn] = __builtin_amdgcn_mfma_f32_16x16x32_bf16(
                    af[fm], bf[fn], acc[fm][fn], 0, 0, 0);
        __syncthreads();
    }

    const int crow = c16 << 2;
    #pragma unroll
    for (int fm = 0; fm < 2; ++fm)
        #pragma unroll
        for (int fn = 0; fn < 4; ++fn)
            #pragma unroll
            for (int r = 0; r < 4; ++r) {
                int rr = m0 + wm * 32 + fm * 16 + crow + r;
                int cc = n0 + wn * 64 + fn * 16 + lr;
                Cb[(long)rr * 512 + cc] = f2bf(EXP2F(TANH_SCALE * acc[fm][fn][r]));
            }
}

// ---------------------------------------------------------------------------
// Kernel A: partial tanh-dot. 1024 blocks = 256 (b,d-pair) x 4 h-chunks
// -> 4 blocks/CU -> 8 waves/SIMD (latency hiding; the R6 version had 1
// block/CU = 2 waves/SIMD and was latency-bound). Each block accumulates
// acc over its 128 h values and writes f32 partials to ws.
// partial layout: [pair 0..255][chunk 0..3][2 rows][512 e]  (4 MB)
// XCD-affinity: xcd=blockIdx&7, b=xcd&3 -> each XCD's L2 sees one 512KB
// Q panel.
// ---------------------------------------------------------------------------
__global__ __launch_bounds__(512)
void attn_partial(const unsigned short* __restrict__ P,  // (B,D,H) bf16 exp2
                  const unsigned short* __restrict__ Q,  // (B,H,E) bf16 exp2
                  const float* __restrict__ vw,          // (H)
                  float* __restrict__ partial) {
    const int g     = blockIdx.x;           // 0..1023
    const int xcd   = g & 7;
    const int b     = xcd & 3;
    const int idx   = g >> 3;               // 0..127
    const int chunk = idx & 3;              // 0..3
    const int dp    = (idx >> 2) + ((xcd >> 2) << 5);  // 0..63
    const int pair  = b * 64 + dp;          // 0..255
    const int bd0   = pair * 2;
    const int e     = threadIdx.x;          // 0..511
    const int h0    = chunk * 128;

    __shared__ float4 combo[128];           // {P0, P1, -2v, pad} (2 KB)
    if (e < 128) {
        int h = h0 + e;
        combo[e] = make_float4(bf2f(P[bd0 * HDIM + h]),
                               bf2f(P[(bd0 + 1) * HDIM + h]),
                               -2.0f * vw[h], 0.0f);
    }
    __syncthreads();

    const unsigned short* qb = Q + b * HDIM * EDIM + h0 * EDIM + e;
    float acc0 = 0.f, acc1 = 0.f;
    #pragma unroll 8
    for (int i = 0; i < 128; ++i) {
        float  q = bf2f(qb[i * EDIM]);
        float4 c = combo[i];
        acc0 = fmaf(c.z, RCPF(fmaf(c.x, q, 1.0f)), acc0);
        acc1 = fmaf(c.z, RCPF(fmaf(c.y, q, 1.0f)), acc1);
    }

    float* pp = partial + (pair * 4 + chunk) * 1024;
    pp[e]       = acc0;
    pp[512 + e] = acc1;
}

// ---------------------------------------------------------------------------
// Kernel B: combine 4 partials + masked log_softmax + write out.
// 256 blocks x 512 threads; 16 KB read/block, trivial compute.
// ---------------------------------------------------------------------------
__global__ __launch_bounds__(512)
void lsm_final(const float* __restrict__ partial,
               const unsigned char* __restrict__ mask,  // (B,E)
               float* __restrict__ out) {               // (B,D,E)
    const int pair = blockIdx.x;       // 0..255 = b*64 + dp
    const int b    = pair >> 6;
    const int bd0  = pair * 2;
    const int e    = threadIdx.x;      // 0..511

    __shared__ float red0[8], red1[8];

    const float* pp = partial + pair * 4096;
    float acc0 = (pp[e]        + pp[1024 + e]) + (pp[2048 + e] + pp[3072 + e]);
    float acc1 = (pp[512 + e]  + pp[1536 + e]) + (pp[2560 + e] + pp[3584 + e]);

    const bool mk = mask[b * EDIM + e];
    float val0 = mk ? -INFINITY : acc0;
    float val1 = mk ? -INFINITY : acc1;

    const int wid = e >> 6, lid = e & 63;

    // --- block max (both rows) ---
    float m0 = val0, m1 = val1;
    #pragma unroll
    for (int o = 32; o >= 1; o >>= 1) {
        m0 = fmaxf(m0, __shfl_xor(m0, o));
        m1 = fmaxf(m1, __shfl_xor(m1, o));
    }
    if (lid == 0) { red0[wid] = m0; red1[wid] = m1; }
    __syncthreads();
    m0 = red0[0]; m1 = red1[0];
    #pragma unroll
    for (int i = 1; i < 8; ++i) { m0 = fmaxf(m0, red0[i]); m1 = fmaxf(m1, red1[i]); }
    __syncthreads();

    // --- block sum of exp(val - m) ---
    float s0 = __expf(val0 - m0), s1 = __expf(val1 - m1);
    #pragma unroll
    for (int o = 32; o >= 1; o >>= 1) {
        s0 += __shfl_xor(s0, o);
        s1 += __shfl_xor(s1, o);
    }
    if (lid == 0) { red0[wid] = s0; red1[wid] = s1; }
    __syncthreads();
    float tot0 = 0.f, tot1 = 0.f;
    #pragma unroll
    for (int i = 0; i < 8; ++i) { tot0 += red0[i]; tot1 += red1[i]; }

    out[(long)bd0 * EDIM + e]       = val0 - m0 - __logf(tot0);
    out[(long)(bd0 + 1) * EDIM + e] = val1 - m1 - __logf(tot1);
}

// ---------------------------------------------------------------------------
extern "C" void kernel_launch(void* const* d_in, const int* in_sizes, int n_in,
                              void* d_out, int out_size, void* d_ws, size_t ws_size,
                              hipStream_t stream) {
    const float*         xdec = (const float*)d_in[0];         // (B,D,H)
    const float*         xenc = (const float*)d_in[1];         // (B,E,H)
    const unsigned char* mask = (const unsigned char*)d_in[2]; // (B,E)
    const float*         W1   = (const float*)d_in[3];         // (H,H)
    const float*         W2   = (const float*)d_in[4];         // (H,H)
    const float*         vw   = (const float*)d_in[5];         // (H)
    float*               out  = (float*)d_out;                 // (B,D,E)

    unsigned short* P = (unsigned short*)d_ws;                 // B*D*H bf16 (512 KB)
    unsigned short* Q = P + (size_t)BATCH * DDIM * HDIM;       // B*H*E bf16 (2 MB)
    float* partial = (float*)(Q + (size_t)BATCH * HDIM * EDIM);// 256*4*1024 f32 (4 MB)

    gemm_both<<<160, 256, 0, stream>>>(xdec, W2, xenc, W1, P, Q);
    attn_partial<<<1024, 512, 0, stream>>>(P, Q, vw, partial);
    lsm_final<<<256, 512, 0, stream>>>(partial, mask, out);
}